// Round 13
// baseline (89.967 us; speedup 1.0000x reference)
//
#include <hip/hip_runtime.h>
#include <hip/hip_bf16.h>

typedef __attribute__((ext_vector_type(8))) short short8;
typedef __attribute__((ext_vector_type(4))) float f32x4;

#define NEG_SLOPE 0.02f

static __device__ __forceinline__ unsigned short f2bf(float f) {
    unsigned int u = __float_as_uint(f);
    u += 0x7fffu + ((u >> 16) & 1u);
    return (unsigned short)(u >> 16);
}

// pack two f32 -> one dword of 2 bf16 (lo, hi) via v_cvt_pk_bf16_f32
static __device__ __forceinline__ unsigned int pk2bf(float lo, float hi) {
    __hip_bfloat162 t = __float22bfloat162_rn(float2{lo, hi});
    unsigned int u;
    __builtin_memcpy(&u, &t, 4);
    return u;
}

#define WROW 304         // elems per co row: 288 used + 16 pad
#define ROW_BYTES 8320   // 65 pairs * 128

// ---------------- prep: weight transforms ----------------
// wb padded: [cc][co][WROW] bf16; wb[cc][co][tap*32+ci5] = conv_w[co][cc*32+ci5][tap]
// pwb[o][k] = bf16(pred_w[o][k]) for o<24, 0 pad to 32 rows  (32*768 bf16)
__global__ __launch_bounds__(256) void prep_kernel(const float* __restrict__ conv_w,
                                                   const float* __restrict__ pred_w,
                                                   unsigned short* __restrict__ wb,
                                                   unsigned short* __restrict__ pwb) {
    int i = blockIdx.x * 256 + threadIdx.x;
    if (i < 2 * 64 * WROW) {
        int cc = i / (64 * WROW);
        int rem = i - cc * (64 * WROW);
        int co = rem / WROW, e = rem - co * WROW;
        float v = 0.0f;
        if (e < 288) {
            int tap = e >> 5, ci5 = e & 31;
            v = conv_w[(co * 64 + cc * 32 + ci5) * 9 + tap];
        }
        wb[i] = f2bf(v);
    }
    if (i < 24576) {
        int o = i / 768, k = i - o * 768;
        pwb[i] = f2bf(o < 24 ? pred_w[o * 768 + k] : 0.0f);
    }
}

// ---------------- fused conv 3x3 + bias + leaky relu (NCHW f32 in, NHWC bf16 out) ----------------
// block: 256 thr = 4 waves; 2 output rows x 128 px x 64 co.
// wave = 2 output rows x 32 px x 64 co: acc[2 row][2 m][4 n] = 16 independent chains, 64 regs.
// A-row reuse: staged rows {dy, dy+1} serve taps for both output rows; 3-buffer rotation
// Ra/Rb/Rc loads each of the 4 staged rows exactly once (24 A-reads/chunk vs 36 naive).
// B-frag read once per (tap,n), feeds 4 MFMAs. LDS reads/CU: 3840 vs R12's 6912 (-45%).
// LDS: weights [64co][WROW] 38,912 B + input 4 x 8320 B = 72,192 B -> 2 blocks/CU.
// Staging identical to R12 (float2 row loads, cvt_pk, conflict-free pair/slot writes).
__global__ __launch_bounds__(256, 2) void conv_mfma(const float* __restrict__ x,
                                                    const unsigned short* __restrict__ wb,
                                                    const float* __restrict__ cb,
                                                    unsigned short* __restrict__ h) {
    __shared__ unsigned short w_sm[64 * WROW];       // 38,912 B
    __shared__ unsigned char in_sm[4 * ROW_BYTES];   // 33,280 B

    // XCD-chunked swizzle: each XCD owns 16 contiguous y rows (8 y-pairs) x all b
    const int id = blockIdx.x;                       // 2048 blocks
    const int xcd = id & 7, local = id >> 3;
    const int b = local & 31;
    const int y0 = ((xcd << 3) + (local >> 5)) * 2;

    const int tid = threadIdx.x;
    const int wave = tid >> 6, lane = tid & 63;
    const int lr = lane & 15, kg = lane >> 4;
    const int px0 = wave * 32;                       // px quarter

    f32x4 acc[2][2][4];                              // [out-row][m][n]
#pragma unroll
    for (int r = 0; r < 2; ++r)
#pragma unroll
        for (int m = 0; m < 2; ++m)
#pragma unroll
            for (int n = 0; n < 4; ++n) acc[r][m][n] = (f32x4){0.f, 0.f, 0.f, 0.f};

    // A-frag base offsets (proven pair/slot swizzle); + staged_row*ROW_BYTES at use
    const unsigned char* ab[2][3];
#pragma unroll
    for (int m = 0; m < 2; ++m)
#pragma unroll
        for (int dx = 0; dx < 3; ++dx) {
            int xx = px0 + m * 16 + lr + dx;         // 0..129
            int pair = xx >> 1, odd = xx & 1;
            int slot = ((odd << 2) | kg) ^ (pair & 7);
            ab[m][dx] = in_sm + pair * 128 + slot * 16;
        }
    const unsigned short* bbp[4];
#pragma unroll
    for (int n = 0; n < 4; ++n) bbp[n] = w_sm + (n * 16 + lr) * WROW + kg * 8;

    // staging geometry: thread = (p_ = pair, q_ = ci oct); covers all 4 rows in a loop
    const int p_ = tid & 63, q_ = tid >> 6;                // p_ 0..63, q_ 0..3
    const int slotA = (4 | q_) ^ (p_ & 7);                 // xx = 2p+1 (odd)
    const int dstA = p_ * 128 + slotA * 16;
    const int slotB = q_ ^ ((p_ + 1) & 7);                 // xx = 2p+2 (even)
    const int dstB = (p_ + 1) * 128 + slotB * 16;

#define LOADROW(DST, R)                                                            \
    {                                                                              \
        _Pragma("unroll")                                                          \
        for (int m_ = 0; m_ < 2; ++m_) {                                           \
            _Pragma("unroll")                                                      \
            for (int d_ = 0; d_ < 3; ++d_)                                         \
                DST[m_][d_] = *(const short8*)(ab[m_][d_] + (R) * ROW_BYTES);      \
        }                                                                          \
    }

#define TAPS(DY, RA, RB)                                                           \
    {                                                                              \
        _Pragma("unroll")                                                          \
        for (int d_ = 0; d_ < 3; ++d_) {                                           \
            _Pragma("unroll")                                                      \
            for (int n_ = 0; n_ < 4; ++n_) {                                       \
                short8 Bf = *(const short8*)(bbp[n_] + ((DY) * 3 + d_) * 32);      \
                acc[0][0][n_] = __builtin_amdgcn_mfma_f32_16x16x32_bf16(RA[0][d_], Bf, acc[0][0][n_], 0, 0, 0); \
                acc[0][1][n_] = __builtin_amdgcn_mfma_f32_16x16x32_bf16(RA[1][d_], Bf, acc[0][1][n_], 0, 0, 0); \
                acc[1][0][n_] = __builtin_amdgcn_mfma_f32_16x16x32_bf16(RB[0][d_], Bf, acc[1][0][n_], 0, 0, 0); \
                acc[1][1][n_] = __builtin_amdgcn_mfma_f32_16x16x32_bf16(RB[1][d_], Bf, acc[1][1][n_], 0, 0, 0); \
            }                                                                      \
        }                                                                          \
    }

    for (int cc = 0; cc < 2; ++cc) {
        __syncthreads();
        // ---- stage weights: linear pre-padded copy, 2432 x 16B ----
        const unsigned short* wsrc = wb + cc * (64 * WROW);
        for (int j = tid; j < 2432; j += 256)
            *(uint4*)(w_sm + j * 8) = *(const uint4*)(wsrc + j * 8);
        // ---- stage input: 4 rows; per row 8 float2 loads -> cvt_pk -> 2 b128 writes ----
        const float* xq = x + ((size_t)b * 64 + cc * 32 + q_ * 8) * 16384;
#pragma unroll
        for (int r = 0; r < 4; ++r) {
            const int gy = y0 + r - 1;
            uint4 Av = {0u, 0u, 0u, 0u}, Bv = {0u, 0u, 0u, 0u};
            if ((unsigned)gy < 128u) {               // block-uniform branch
                const float* s = xq + gy * 128 + 2 * p_;
                float2 f[8];
#pragma unroll
                for (int c = 0; c < 8; ++c) f[c] = *(const float2*)(s + (size_t)c * 16384);
                Av.x = pk2bf(f[0].x, f[1].x); Av.y = pk2bf(f[2].x, f[3].x);
                Av.z = pk2bf(f[4].x, f[5].x); Av.w = pk2bf(f[6].x, f[7].x);
                Bv.x = pk2bf(f[0].y, f[1].y); Bv.y = pk2bf(f[2].y, f[3].y);
                Bv.z = pk2bf(f[4].y, f[5].y); Bv.w = pk2bf(f[6].y, f[7].y);
            }
            *(uint4*)(in_sm + r * ROW_BYTES + dstA) = Av;
            *(uint4*)(in_sm + r * ROW_BYTES + dstB) = Bv;
        }
        // ---- tail: zero xx=0 (pair0,odd0) and xx=129 (pair64,odd1), all 4 rows ----
        if (tid < 32) {
            int q = tid & 3, r = (tid >> 2) & 3, which = tid >> 4;
            int dst = which == 0 ? (q * 16) : (64 * 128 + (4 | q) * 16);
            *(uint4*)(in_sm + r * ROW_BYTES + dst) = (uint4){0u, 0u, 0u, 0u};
        }
        __syncthreads();

        // ---- compute: 9 taps, A-row rotation; out0 uses staged row dy, out1 row dy+1 ----
        short8 Ra[2][3], Rb[2][3], Rc[2][3];
        LOADROW(Ra, 0)
        LOADROW(Rb, 1)
        LOADROW(Rc, 2)        // issued early, consumed at dy=1
        TAPS(0, Ra, Rb)
        LOADROW(Ra, 3)        // Ra dead after dy=0; row 3 in flight under dy=1
        TAPS(1, Rb, Rc)
        TAPS(2, Rc, Ra)
    }

#undef LOADROW
#undef TAPS

    // ---- epilogue: bias + leaky relu, bf16 NHWC store, 2 rows ----
    float bias[4];
#pragma unroll
    for (int n = 0; n < 4; ++n) bias[n] = cb[n * 16 + lr];
#pragma unroll
    for (int r = 0; r < 2; ++r) {
        const size_t hrow = (size_t)(b * 128 + y0 + r) * 128;
#pragma unroll
        for (int m = 0; m < 2; ++m)
#pragma unroll
            for (int rr = 0; rr < 4; ++rr) {
                const int p = px0 + m * 16 + kg * 4 + rr;
                unsigned short* hp = h + (hrow + p) * 64 + lr;
#pragma unroll
                for (int n = 0; n < 4; ++n) {
                    float v = acc[r][m][n][rr] + bias[n];
                    v = v > 0.0f ? v : NEG_SLOPE * v;
                    hp[n * 16] = f2bf(v);
                }
            }
    }
}

// ---------------- gather + (pairs x 768)·(768 x 24) GEMM via MFMA ----------------
__global__ __launch_bounds__(256) void gather_gemm(const unsigned short* __restrict__ h,
                                                   const int* __restrict__ pos,
                                                   const unsigned short* __restrict__ pw,
                                                   const float* __restrict__ pred_b,
                                                   float* __restrict__ out) {
    __shared__ unsigned char pw_lds[32 * 1536];   // 32 rows x 768 bf16, swizzled
    const int tid = threadIdx.x;

    for (int i = tid; i < 3072; i += 256) {       // 3072 chunks of 16B
        int row = i / 96, c = i - row * 96;
        int dst = row * 1536 + ((c * 16) ^ ((row & 7) << 4));
        *(uint4*)(pw_lds + dst) = ((const uint4*)pw)[i];
    }
    __syncthreads();

    const int wave = tid >> 6, lane = tid & 63;
    const int pair_base = blockIdx.x * 64 + wave * 16;
    const int prow = lane & 15;
    const int kgrp = lane >> 4;
    const int pair = pair_base + prow;
    const int b = pair & 31;
    const unsigned short* hb = h + (size_t)b * 16384 * 64;

    const int swz0 = (prow & 7) << 4;
    const unsigned char* bro0 = pw_lds + prow * 1536;
    const unsigned char* bro1 = pw_lds + (prow + 16) * 1536;

    f32x4 acc0 = {0.f, 0.f, 0.f, 0.f};
    f32x4 acc1 = {0.f, 0.f, 0.f, 0.f};

#pragma unroll
    for (int l = 0; l < 12; ++l) {
        int2 pq = ((const int2*)pos)[pair * 12 + l];
        int px = pq.x < 0 ? 0 : (pq.x > 127 ? 127 : pq.x);
        int py = pq.y < 0 ? 0 : (pq.y > 127 ? 127 : pq.y);
        const unsigned short* pix = hb + (((size_t)py << 7) + px) * 64;
#pragma unroll
        for (int half = 0; half < 2; ++half) {
            const int c0 = half * 32 + kgrp * 8;
            short8 a = *(const short8*)(pix + c0);
            const int kb = (l * 64 + half * 32 + kgrp * 8) * 2;
            short8 b0 = *(const short8*)(bro0 + (kb ^ swz0));
            short8 b1 = *(const short8*)(bro1 + (kb ^ swz0));
            acc0 = __builtin_amdgcn_mfma_f32_16x16x32_bf16(a, b0, acc0, 0, 0, 0);
            acc1 = __builtin_amdgcn_mfma_f32_16x16x32_bf16(a, b1, acc1, 0, 0, 0);
        }
    }

    const int o0 = lane & 15;
    const float bias0 = pred_b[o0];
    const float bias1 = (o0 + 16 < 24) ? pred_b[o0 + 16] : 0.0f;
#pragma unroll
    for (int r = 0; r < 4; ++r) {
        const int pout = pair_base + (lane >> 4) * 4 + r;
        out[(size_t)pout * 24 + o0] = acc0[r] + bias0;
        if (o0 + 16 < 24)
            out[(size_t)pout * 24 + o0 + 16] = acc1[r] + bias1;
    }
}

extern "C" void kernel_launch(void* const* d_in, const int* in_sizes, int n_in,
                              void* d_out, int out_size, void* d_ws, size_t ws_size,
                              hipStream_t stream) {
    const float* x      = (const float*)d_in[0];
    const int*   pos    = (const int*)d_in[1];
    const float* conv_w = (const float*)d_in[2];
    const float* conv_b = (const float*)d_in[3];
    const float* pred_w = (const float*)d_in[4];
    const float* pred_b = (const float*)d_in[5];
    float* out = (float*)d_out;

    char* ws = (char*)d_ws;
    unsigned short* h   = (unsigned short*)ws;                        // 67,108,864 B
    unsigned short* wb  = (unsigned short*)(ws + 67108864);           // 77,824 B
    unsigned short* pwb = (unsigned short*)(ws + 67108864 + 77824);   // 49,152 B

    prep_kernel<<<152, 256, 0, stream>>>(conv_w, pred_w, wb, pwb);
    conv_mfma<<<2048, 256, 0, stream>>>(x, wb, conv_b, h);
    gather_gemm<<<500, 256, 0, stream>>>(h, pos, pwb, pred_b, out);
}

// Round 14
// 86.097 us; speedup vs baseline: 1.0450x; 1.0450x over previous
//
#include <hip/hip_runtime.h>
#include <hip/hip_bf16.h>

typedef __attribute__((ext_vector_type(8))) short short8;
typedef __attribute__((ext_vector_type(4))) float f32x4;

#define NEG_SLOPE 0.02f

static __device__ __forceinline__ unsigned short f2bf(float f) {
    unsigned int u = __float_as_uint(f);
    u += 0x7fffu + ((u >> 16) & 1u);
    return (unsigned short)(u >> 16);
}

// pack two f32 -> one dword of 2 bf16 (lo, hi) via v_cvt_pk_bf16_f32
static __device__ __forceinline__ unsigned int pk2bf(float lo, float hi) {
    __hip_bfloat162 t = __float22bfloat162_rn(float2{lo, hi});
    unsigned int u;
    __builtin_memcpy(&u, &t, 4);
    return u;
}

#define WROW 304         // elems per co row: 288 used + 16 pad (152 dw == 24 mod 32, ~floor)
#define ROW_BYTES 8320   // 65 pairs * 128

// ---------------- prep: weight transforms ----------------
// wb padded: [cc][co][WROW] bf16; wb[cc][co][tap*32+ci5] = conv_w[co][cc*32+ci5][tap]
// pwb[o][k] = bf16(pred_w[o][k]) for o<24, 0 pad to 32 rows  (32*768 bf16)
__global__ __launch_bounds__(256) void prep_kernel(const float* __restrict__ conv_w,
                                                   const float* __restrict__ pred_w,
                                                   unsigned short* __restrict__ wb,
                                                   unsigned short* __restrict__ pwb) {
    int i = blockIdx.x * 256 + threadIdx.x;
    if (i < 2 * 64 * WROW) {
        int cc = i / (64 * WROW);
        int rem = i - cc * (64 * WROW);
        int co = rem / WROW, e = rem - co * WROW;
        float v = 0.0f;
        if (e < 288) {
            int tap = e >> 5, ci5 = e & 31;
            v = conv_w[(co * 64 + cc * 32 + ci5) * 9 + tap];
        }
        wb[i] = f2bf(v);
    }
    if (i < 24576) {
        int o = i / 768, k = i - o * 768;
        pwb[i] = f2bf(o < 24 ? pred_w[o * 768 + k] : 0.0f);
    }
}

// ---------------- fused conv 3x3 + bias + leaky relu (NCHW f32 in, NHWC bf16 out) ----------------
// R12 structure (best measured): 512 thr = 8 waves; 2 output rows x 128 px x 64 co.
// wave = 32 px x 64 co (2m x 4n, 8 independent MFMA chains). LDS 72,192 B -> 2 blocks/CU,
// 4 waves/SIMD. float2 staging + cvt_pk + conflict-free pair/slot writes; T14 chunk-1
// global loads in flight across chunk-0 compute.
__global__ __launch_bounds__(512, 4) void conv_mfma(const float* __restrict__ x,
                                                    const unsigned short* __restrict__ wb,
                                                    const float* __restrict__ cb,
                                                    unsigned short* __restrict__ h) {
    __shared__ unsigned short w_sm[64 * WROW];       // 38,912 B
    __shared__ unsigned char in_sm[4 * ROW_BYTES];   // 33,280 B

    // XCD-chunked swizzle: each XCD owns 16 contiguous y rows (8 y-pairs) x all b
    const int id = blockIdx.x;                       // 2048 blocks
    const int xcd = id & 7, local = id >> 3;
    const int b = local & 31;
    const int y0 = ((xcd << 3) + (local >> 5)) * 2;

    const int tid = threadIdx.x;
    const int wave = tid >> 6, lane = tid & 63;
    const int lr = lane & 15, kg = lane >> 4;
    const int ro = wave >> 2;                        // output row within block (0/1)
    const int px0 = (wave & 3) * 32;                 // px quarter
    const int y = y0 + ro;

    f32x4 acc[2][4];
#pragma unroll
    for (int m = 0; m < 2; ++m)
#pragma unroll
        for (int n = 0; n < 4; ++n) acc[m][n] = (f32x4){0.f, 0.f, 0.f, 0.f};

    // A-frag base offsets (proven pair/slot swizzle), (ro+dy)*ROW_BYTES added at use
    const unsigned char* ab[2][3];
#pragma unroll
    for (int m = 0; m < 2; ++m)
#pragma unroll
        for (int dx = 0; dx < 3; ++dx) {
            int xx = px0 + m * 16 + lr + dx;         // 0..129
            int pair = xx >> 1, odd = xx & 1;
            int slot = ((odd << 2) | kg) ^ (pair & 7);
            ab[m][dx] = in_sm + pair * 128 + slot * 16;
        }
    const unsigned short* bbp[4];
#pragma unroll
    for (int n = 0; n < 4; ++n) bbp[n] = w_sm + (n * 16 + lr) * WROW + kg * 8;

    // staging geometry: thread = (p_ = pair, q_ = ci oct, rr_ = row parity)
    const int p_ = tid & 63, q_ = (tid >> 6) & 3, rr_ = tid >> 8;
    const int slotA = (4 | q_) ^ (p_ & 7);                 // xx = 2p+1 (odd)
    const int dstA = p_ * 128 + slotA * 16;
    const int slotB = q_ ^ ((p_ + 1) & 7);                 // xx = 2p+2 (even)
    const int dstB = (p_ + 1) * 128 + slotB * 16;

    float2 F[2][8];   // in-flight staging registers (indices static under unroll)

#define LOADX(CCI)                                                                 \
    {                                                                              \
        const float* xq_ = x + ((size_t)b * 64 + (CCI) * 32 + q_ * 8) * 16384;     \
        _Pragma("unroll")                                                          \
        for (int pass = 0; pass < 2; ++pass) {                                     \
            const int r_ = pass * 2 + rr_;                                         \
            const int gy_ = y0 + r_ - 1;                                           \
            if ((unsigned)gy_ < 128u) {                                            \
                const float* s_ = xq_ + gy_ * 128 + 2 * p_;                        \
                _Pragma("unroll")                                                  \
                for (int c = 0; c < 8; ++c)                                        \
                    F[pass][c] = *(const float2*)(s_ + (size_t)c * 16384);         \
            } else {                                                               \
                _Pragma("unroll")                                                  \
                for (int c = 0; c < 8; ++c) F[pass][c] = (float2){0.f, 0.f};       \
            }                                                                      \
        }                                                                          \
    }

#define STOREX()                                                                   \
    {                                                                              \
        _Pragma("unroll")                                                          \
        for (int pass = 0; pass < 2; ++pass) {                                     \
            const int r_ = pass * 2 + rr_;                                         \
            uint4 Av, Bv;                                                          \
            Av.x = pk2bf(F[pass][0].x, F[pass][1].x);                              \
            Av.y = pk2bf(F[pass][2].x, F[pass][3].x);                              \
            Av.z = pk2bf(F[pass][4].x, F[pass][5].x);                              \
            Av.w = pk2bf(F[pass][6].x, F[pass][7].x);                              \
            Bv.x = pk2bf(F[pass][0].y, F[pass][1].y);                              \
            Bv.y = pk2bf(F[pass][2].y, F[pass][3].y);                              \
            Bv.z = pk2bf(F[pass][4].y, F[pass][5].y);                              \
            Bv.w = pk2bf(F[pass][6].y, F[pass][7].y);                              \
            *(uint4*)(in_sm + r_ * ROW_BYTES + dstA) = Av;                         \
            *(uint4*)(in_sm + r_ * ROW_BYTES + dstB) = Bv;                         \
        }                                                                          \
    }

#define STAGEW(CCI)                                                                \
    {                                                                              \
        const unsigned short* wsrc_ = wb + (CCI) * (64 * WROW);                    \
        for (int j = tid; j < 2432; j += 512)                                      \
            *(uint4*)(w_sm + j * 8) = *(const uint4*)(wsrc_ + j * 8);              \
    }

#define TAILZ()                                                                    \
    if (tid < 32) {                                                                \
        int q = tid & 3, r = (tid >> 2) & 3, which = tid >> 4;                     \
        int dst = which == 0 ? (q * 16) : (64 * 128 + (4 | q) * 16);               \
        *(uint4*)(in_sm + r * ROW_BYTES + dst) = (uint4){0u, 0u, 0u, 0u};          \
    }

#define COMPUTE()                                                                  \
    _Pragma("unroll")                                                              \
    for (int t = 0; t < 9; ++t) {                                                  \
        const int dy = t / 3, dx = t % 3;                                          \
        const int aoff = (ro + dy) * ROW_BYTES;                                    \
        short8 A0 = *(const short8*)(ab[0][dx] + aoff);                            \
        short8 A1 = *(const short8*)(ab[1][dx] + aoff);                            \
        _Pragma("unroll")                                                          \
        for (int n = 0; n < 4; ++n) {                                              \
            short8 B = *(const short8*)(bbp[n] + t * 32);                          \
            acc[0][n] = __builtin_amdgcn_mfma_f32_16x16x32_bf16(A0, B, acc[0][n], 0, 0, 0); \
            acc[1][n] = __builtin_amdgcn_mfma_f32_16x16x32_bf16(A1, B, acc[1][n], 0, 0, 0); \
        }                                                                          \
    }

    // ---- chunk 0 ----
    LOADX(0)
    STAGEW(0)
    STOREX()
    TAILZ()
    LOADX(1)            // T14: chunk-1 loads in flight across chunk-0 compute
    __syncthreads();
    COMPUTE()
    // ---- chunk 1 ----
    __syncthreads();
    STAGEW(1)
    STOREX()
    TAILZ()
    __syncthreads();
    COMPUTE()

#undef LOADX
#undef STOREX
#undef STAGEW
#undef TAILZ
#undef COMPUTE

    // ---- epilogue: bias + leaky relu, bf16 NHWC store ----
    float bias[4];
#pragma unroll
    for (int n = 0; n < 4; ++n) bias[n] = cb[n * 16 + lr];
    const size_t hrow = (size_t)(b * 128 + y) * 128;
#pragma unroll
    for (int m = 0; m < 2; ++m)
#pragma unroll
        for (int rr = 0; rr < 4; ++rr) {
            const int p = px0 + m * 16 + kg * 4 + rr;
            unsigned short* hp = h + (hrow + p) * 64 + lr;
#pragma unroll
            for (int n = 0; n < 4; ++n) {
                float v = acc[m][n][rr] + bias[n];
                v = v > 0.0f ? v : NEG_SLOPE * v;
                hp[n * 16] = f2bf(v);
            }
        }
}

// ---------------- gather + (pairs x 768)·(768 x 24) GEMM via MFMA ----------------
// 4 independent accumulator chains (l 0-5 -> accXa, l 6-11 -> accXb) to break the
// dependent-MFMA latency chain at 2 waves/SIMD (LDS-capped occupancy). Exact f32 sum
// of the two halves in the epilogue.
__global__ __launch_bounds__(256) void gather_gemm(const unsigned short* __restrict__ h,
                                                   const int* __restrict__ pos,
                                                   const unsigned short* __restrict__ pw,
                                                   const float* __restrict__ pred_b,
                                                   float* __restrict__ out) {
    __shared__ unsigned char pw_lds[32 * 1536];   // 32 rows x 768 bf16, swizzled
    const int tid = threadIdx.x;

    for (int i = tid; i < 3072; i += 256) {       // 3072 chunks of 16B
        int row = i / 96, c = i - row * 96;
        int dst = row * 1536 + ((c * 16) ^ ((row & 7) << 4));
        *(uint4*)(pw_lds + dst) = ((const uint4*)pw)[i];
    }
    __syncthreads();

    const int wave = tid >> 6, lane = tid & 63;
    const int pair_base = blockIdx.x * 64 + wave * 16;
    const int prow = lane & 15;
    const int kgrp = lane >> 4;
    const int pair = pair_base + prow;
    const int b = pair & 31;
    const unsigned short* hb = h + (size_t)b * 16384 * 64;

    const int swz0 = (prow & 7) << 4;
    const unsigned char* bro0 = pw_lds + prow * 1536;
    const unsigned char* bro1 = pw_lds + (prow + 16) * 1536;

    f32x4 acc0a = {0.f, 0.f, 0.f, 0.f};
    f32x4 acc1a = {0.f, 0.f, 0.f, 0.f};
    f32x4 acc0b = {0.f, 0.f, 0.f, 0.f};
    f32x4 acc1b = {0.f, 0.f, 0.f, 0.f};

#pragma unroll
    for (int l = 0; l < 12; ++l) {
        int2 pq = ((const int2*)pos)[pair * 12 + l];
        int px = pq.x < 0 ? 0 : (pq.x > 127 ? 127 : pq.x);
        int py = pq.y < 0 ? 0 : (pq.y > 127 ? 127 : pq.y);
        const unsigned short* pix = hb + (((size_t)py << 7) + px) * 64;
#pragma unroll
        for (int half = 0; half < 2; ++half) {
            const int c0 = half * 32 + kgrp * 8;
            short8 a = *(const short8*)(pix + c0);
            const int kb = (l * 64 + half * 32 + kgrp * 8) * 2;
            short8 b0 = *(const short8*)(bro0 + (kb ^ swz0));
            short8 b1 = *(const short8*)(bro1 + (kb ^ swz0));
            if (l < 6) {
                acc0a = __builtin_amdgcn_mfma_f32_16x16x32_bf16(a, b0, acc0a, 0, 0, 0);
                acc1a = __builtin_amdgcn_mfma_f32_16x16x32_bf16(a, b1, acc1a, 0, 0, 0);
            } else {
                acc0b = __builtin_amdgcn_mfma_f32_16x16x32_bf16(a, b0, acc0b, 0, 0, 0);
                acc1b = __builtin_amdgcn_mfma_f32_16x16x32_bf16(a, b1, acc1b, 0, 0, 0);
            }
        }
    }

    const int o0 = lane & 15;
    const float bias0 = pred_b[o0];
    const float bias1 = (o0 + 16 < 24) ? pred_b[o0 + 16] : 0.0f;
#pragma unroll
    for (int r = 0; r < 4; ++r) {
        const int pout = pair_base + (lane >> 4) * 4 + r;
        out[(size_t)pout * 24 + o0] = acc0a[r] + acc0b[r] + bias0;
        if (o0 + 16 < 24)
            out[(size_t)pout * 24 + o0 + 16] = acc1a[r] + acc1b[r] + bias1;
    }
}

extern "C" void kernel_launch(void* const* d_in, const int* in_sizes, int n_in,
                              void* d_out, int out_size, void* d_ws, size_t ws_size,
                              hipStream_t stream) {
    const float* x      = (const float*)d_in[0];
    const int*   pos    = (const int*)d_in[1];
    const float* conv_w = (const float*)d_in[2];
    const float* conv_b = (const float*)d_in[3];
    const float* pred_w = (const float*)d_in[4];
    const float* pred_b = (const float*)d_in[5];
    float* out = (float*)d_out;

    char* ws = (char*)d_ws;
    unsigned short* h   = (unsigned short*)ws;                        // 67,108,864 B
    unsigned short* wb  = (unsigned short*)(ws + 67108864);           // 77,824 B
    unsigned short* pwb = (unsigned short*)(ws + 67108864 + 77824);   // 49,152 B

    prep_kernel<<<152, 256, 0, stream>>>(conv_w, pred_w, wb, pwb);
    conv_mfma<<<2048, 512, 0, stream>>>(x, wb, conv_b, h);
    gather_gemm<<<500, 256, 0, stream>>>(h, pos, pwb, pred_b, out);
}

// Round 15
// 84.636 us; speedup vs baseline: 1.0630x; 1.0173x over previous
//
#include <hip/hip_runtime.h>
#include <hip/hip_bf16.h>

typedef __attribute__((ext_vector_type(8))) short short8;
typedef __attribute__((ext_vector_type(4))) float f32x4;

#define NEG_SLOPE 0.02f

static __device__ __forceinline__ unsigned short f2bf(float f) {
    unsigned int u = __float_as_uint(f);
    u += 0x7fffu + ((u >> 16) & 1u);
    return (unsigned short)(u >> 16);
}

// pack two f32 -> one dword of 2 bf16 (lo, hi) via v_cvt_pk_bf16_f32
static __device__ __forceinline__ unsigned int pk2bf(float lo, float hi) {
    __hip_bfloat162 t = __float22bfloat162_rn(float2{lo, hi});
    unsigned int u;
    __builtin_memcpy(&u, &t, 4);
    return u;
}

// async global->LDS, 16 B per lane; LDS dest must be wave-uniform base + lane*16
static __device__ __forceinline__ void gld_lds16(const unsigned short* g, unsigned short* l) {
    __builtin_amdgcn_global_load_lds(
        (const __attribute__((address_space(1))) unsigned int*)g,
        (__attribute__((address_space(3))) unsigned int*)(void*)l,
        16, 0, 0);
}

#define WROW 304         // elems per co row: 288 used + 16 pad (152 dw == 24 mod 32, ~floor)
#define ROW_BYTES 8320   // 65 pairs * 128

// ---------------- prep: weight transforms ----------------
// wb padded: [cc][co][WROW] bf16; wb[cc][co][tap*32+ci5] = conv_w[co][cc*32+ci5][tap]
// pwb[o][k] = bf16(pred_w[o][k]) for o<24, 0 pad to 32 rows  (32*768 bf16)
__global__ __launch_bounds__(256) void prep_kernel(const float* __restrict__ conv_w,
                                                   const float* __restrict__ pred_w,
                                                   unsigned short* __restrict__ wb,
                                                   unsigned short* __restrict__ pwb) {
    int i = blockIdx.x * 256 + threadIdx.x;
    if (i < 2 * 64 * WROW) {
        int cc = i / (64 * WROW);
        int rem = i - cc * (64 * WROW);
        int co = rem / WROW, e = rem - co * WROW;
        float v = 0.0f;
        if (e < 288) {
            int tap = e >> 5, ci5 = e & 31;
            v = conv_w[(co * 64 + cc * 32 + ci5) * 9 + tap];
        }
        wb[i] = f2bf(v);
    }
    if (i < 24576) {
        int o = i / 768, k = i - o * 768;
        pwb[i] = f2bf(o < 24 ? pred_w[o * 768 + k] : 0.0f);
    }
}

// ---------------- fused conv 3x3 + bias + leaky relu (NCHW f32 in, NHWC bf16 out) ----------------
// R12 structure (best measured): 512 thr = 8 waves; 2 output rows x 128 px x 64 co.
// wave = 32 px x 64 co (2m x 4n, 8 independent MFMA chains). LDS 72,192 B -> 2 blocks/CU,
// 4 waves/SIMD. float2 staging + cvt_pk + conflict-free pair/slot writes; T14 chunk-1
// global loads in flight across chunk-0 compute. Weight staging via global_load_lds
// (width 16): lane j0+tid -> w_sm + (j0+tid)*16 B = wave-uniform base + lane*16.
__global__ __launch_bounds__(512, 4) void conv_mfma(const float* __restrict__ x,
                                                    const unsigned short* __restrict__ wb,
                                                    const float* __restrict__ cb,
                                                    unsigned short* __restrict__ h) {
    __shared__ unsigned short w_sm[64 * WROW];       // 38,912 B
    __shared__ unsigned char in_sm[4 * ROW_BYTES];   // 33,280 B

    // XCD-chunked swizzle: each XCD owns 16 contiguous y rows (8 y-pairs) x all b
    const int id = blockIdx.x;                       // 2048 blocks
    const int xcd = id & 7, local = id >> 3;
    const int b = local & 31;
    const int y0 = ((xcd << 3) + (local >> 5)) * 2;

    const int tid = threadIdx.x;
    const int wave = tid >> 6, lane = tid & 63;
    const int lr = lane & 15, kg = lane >> 4;
    const int ro = wave >> 2;                        // output row within block (0/1)
    const int px0 = (wave & 3) * 32;                 // px quarter
    const int y = y0 + ro;

    f32x4 acc[2][4];
#pragma unroll
    for (int m = 0; m < 2; ++m)
#pragma unroll
        for (int n = 0; n < 4; ++n) acc[m][n] = (f32x4){0.f, 0.f, 0.f, 0.f};

    // A-frag base offsets (proven pair/slot swizzle), (ro+dy)*ROW_BYTES added at use
    const unsigned char* ab[2][3];
#pragma unroll
    for (int m = 0; m < 2; ++m)
#pragma unroll
        for (int dx = 0; dx < 3; ++dx) {
            int xx = px0 + m * 16 + lr + dx;         // 0..129
            int pair = xx >> 1, odd = xx & 1;
            int slot = ((odd << 2) | kg) ^ (pair & 7);
            ab[m][dx] = in_sm + pair * 128 + slot * 16;
        }
    const unsigned short* bbp[4];
#pragma unroll
    for (int n = 0; n < 4; ++n) bbp[n] = w_sm + (n * 16 + lr) * WROW + kg * 8;

    // staging geometry: thread = (p_ = pair, q_ = ci oct, rr_ = row parity)
    const int p_ = tid & 63, q_ = (tid >> 6) & 3, rr_ = tid >> 8;
    const int slotA = (4 | q_) ^ (p_ & 7);                 // xx = 2p+1 (odd)
    const int dstA = p_ * 128 + slotA * 16;
    const int slotB = q_ ^ ((p_ + 1) & 7);                 // xx = 2p+2 (even)
    const int dstB = (p_ + 1) * 128 + slotB * 16;

    float2 F[2][8];   // in-flight staging registers (indices static under unroll)

#define LOADX(CCI)                                                                 \
    {                                                                              \
        const float* xq_ = x + ((size_t)b * 64 + (CCI) * 32 + q_ * 8) * 16384;     \
        _Pragma("unroll")                                                          \
        for (int pass = 0; pass < 2; ++pass) {                                     \
            const int r_ = pass * 2 + rr_;                                         \
            const int gy_ = y0 + r_ - 1;                                           \
            if ((unsigned)gy_ < 128u) {                                            \
                const float* s_ = xq_ + gy_ * 128 + 2 * p_;                        \
                _Pragma("unroll")                                                  \
                for (int c = 0; c < 8; ++c)                                        \
                    F[pass][c] = *(const float2*)(s_ + (size_t)c * 16384);         \
            } else {                                                               \
                _Pragma("unroll")                                                  \
                for (int c = 0; c < 8; ++c) F[pass][c] = (float2){0.f, 0.f};       \
            }                                                                      \
        }                                                                          \
    }

#define STOREX()                                                                   \
    {                                                                              \
        _Pragma("unroll")                                                          \
        for (int pass = 0; pass < 2; ++pass) {                                     \
            const int r_ = pass * 2 + rr_;                                         \
            uint4 Av, Bv;                                                          \
            Av.x = pk2bf(F[pass][0].x, F[pass][1].x);                              \
            Av.y = pk2bf(F[pass][2].x, F[pass][3].x);                              \
            Av.z = pk2bf(F[pass][4].x, F[pass][5].x);                              \
            Av.w = pk2bf(F[pass][6].x, F[pass][7].x);                              \
            Bv.x = pk2bf(F[pass][0].y, F[pass][1].y);                              \
            Bv.y = pk2bf(F[pass][2].y, F[pass][3].y);                              \
            Bv.z = pk2bf(F[pass][4].y, F[pass][5].y);                              \
            Bv.w = pk2bf(F[pass][6].y, F[pass][7].y);                              \
            *(uint4*)(in_sm + r_ * ROW_BYTES + dstA) = Av;                         \
            *(uint4*)(in_sm + r_ * ROW_BYTES + dstB) = Bv;                         \
        }                                                                          \
    }

#define STAGEW(CCI)                                                                \
    {                                                                              \
        const unsigned short* wsrc_ = wb + (CCI) * (64 * WROW);                    \
        _Pragma("unroll")                                                          \
        for (int j0 = 0; j0 < 2560; j0 += 512) {                                   \
            int j_ = j0 + tid;                                                     \
            if (j_ < 2432) gld_lds16(wsrc_ + j_ * 8, w_sm + j_ * 8);               \
        }                                                                          \
    }

#define TAILZ()                                                                    \
    if (tid < 32) {                                                                \
        int q = tid & 3, r = (tid >> 2) & 3, which = tid >> 4;                     \
        int dst = which == 0 ? (q * 16) : (64 * 128 + (4 | q) * 16);               \
        *(uint4*)(in_sm + r * ROW_BYTES + dst) = (uint4){0u, 0u, 0u, 0u};          \
    }

#define COMPUTE()                                                                  \
    _Pragma("unroll")                                                              \
    for (int t = 0; t < 9; ++t) {                                                  \
        const int dy = t / 3, dx = t % 3;                                          \
        const int aoff = (ro + dy) * ROW_BYTES;                                    \
        short8 A0 = *(const short8*)(ab[0][dx] + aoff);                            \
        short8 A1 = *(const short8*)(ab[1][dx] + aoff);                            \
        _Pragma("unroll")                                                          \
        for (int n = 0; n < 4; ++n) {                                              \
            short8 B = *(const short8*)(bbp[n] + t * 32);                          \
            acc[0][n] = __builtin_amdgcn_mfma_f32_16x16x32_bf16(A0, B, acc[0][n], 0, 0, 0); \
            acc[1][n] = __builtin_amdgcn_mfma_f32_16x16x32_bf16(A1, B, acc[1][n], 0, 0, 0); \
        }                                                                          \
    }

    // ---- chunk 0 ----
    LOADX(0)
    STAGEW(0)
    STOREX()
    TAILZ()
    LOADX(1)            // T14: chunk-1 loads in flight across chunk-0 compute
    __syncthreads();
    COMPUTE()
    // ---- chunk 1 ----
    __syncthreads();
    STAGEW(1)
    STOREX()
    TAILZ()
    __syncthreads();
    COMPUTE()

#undef LOADX
#undef STOREX
#undef STAGEW
#undef TAILZ
#undef COMPUTE

    // ---- epilogue: bias + leaky relu, bf16 NHWC store ----
    float bias[4];
#pragma unroll
    for (int n = 0; n < 4; ++n) bias[n] = cb[n * 16 + lr];
    const size_t hrow = (size_t)(b * 128 + y) * 128;
#pragma unroll
    for (int m = 0; m < 2; ++m)
#pragma unroll
        for (int rr = 0; rr < 4; ++rr) {
            const int p = px0 + m * 16 + kg * 4 + rr;
            unsigned short* hp = h + (hrow + p) * 64 + lr;
#pragma unroll
            for (int n = 0; n < 4; ++n) {
                float v = acc[m][n][rr] + bias[n];
                v = v > 0.0f ? v : NEG_SLOPE * v;
                hp[n * 16] = f2bf(v);
            }
        }
}

// ---------------- gather + (pairs x 768)·(768 x 24) GEMM via MFMA ----------------
// __launch_bounds__(256, 2): 2 waves/EU floor == current grid-capped occupancy, but
// raises the VGPR budget (52 -> up to 256) so the unrolled 12x2 pixel-load stream can
// be hoisted into flight instead of serializing one L2/L3 gather latency per MFMA pair.
// 4 independent accumulator chains (l 0-5 / 6-11) kept from R14.
__global__ __launch_bounds__(256, 2) void gather_gemm(const unsigned short* __restrict__ h,
                                                      const int* __restrict__ pos,
                                                      const unsigned short* __restrict__ pw,
                                                      const float* __restrict__ pred_b,
                                                      float* __restrict__ out) {
    __shared__ unsigned char pw_lds[32 * 1536];   // 32 rows x 768 bf16, swizzled
    const int tid = threadIdx.x;

    for (int i = tid; i < 3072; i += 256) {       // 3072 chunks of 16B
        int row = i / 96, c = i - row * 96;
        int dst = row * 1536 + ((c * 16) ^ ((row & 7) << 4));
        *(uint4*)(pw_lds + dst) = ((const uint4*)pw)[i];
    }
    __syncthreads();

    const int wave = tid >> 6, lane = tid & 63;
    const int pair_base = blockIdx.x * 64 + wave * 16;
    const int prow = lane & 15;
    const int kgrp = lane >> 4;
    const int pair = pair_base + prow;
    const int b = pair & 31;
    const unsigned short* hb = h + (size_t)b * 16384 * 64;

    const int swz0 = (prow & 7) << 4;
    const unsigned char* bro0 = pw_lds + prow * 1536;
    const unsigned char* bro1 = pw_lds + (prow + 16) * 1536;

    f32x4 acc0a = {0.f, 0.f, 0.f, 0.f};
    f32x4 acc1a = {0.f, 0.f, 0.f, 0.f};
    f32x4 acc0b = {0.f, 0.f, 0.f, 0.f};
    f32x4 acc1b = {0.f, 0.f, 0.f, 0.f};

#pragma unroll
    for (int l = 0; l < 12; ++l) {
        int2 pq = ((const int2*)pos)[pair * 12 + l];
        int px = pq.x < 0 ? 0 : (pq.x > 127 ? 127 : pq.x);
        int py = pq.y < 0 ? 0 : (pq.y > 127 ? 127 : pq.y);
        const unsigned short* pix = hb + (((size_t)py << 7) + px) * 64;
#pragma unroll
        for (int half = 0; half < 2; ++half) {
            const int c0 = half * 32 + kgrp * 8;
            short8 a = *(const short8*)(pix + c0);
            const int kb = (l * 64 + half * 32 + kgrp * 8) * 2;
            short8 b0 = *(const short8*)(bro0 + (kb ^ swz0));
            short8 b1 = *(const short8*)(bro1 + (kb ^ swz0));
            if (l < 6) {
                acc0a = __builtin_amdgcn_mfma_f32_16x16x32_bf16(a, b0, acc0a, 0, 0, 0);
                acc1a = __builtin_amdgcn_mfma_f32_16x16x32_bf16(a, b1, acc1a, 0, 0, 0);
            } else {
                acc0b = __builtin_amdgcn_mfma_f32_16x16x32_bf16(a, b0, acc0b, 0, 0, 0);
                acc1b = __builtin_amdgcn_mfma_f32_16x16x32_bf16(a, b1, acc1b, 0, 0, 0);
            }
        }
    }

    const int o0 = lane & 15;
    const float bias0 = pred_b[o0];
    const float bias1 = (o0 + 16 < 24) ? pred_b[o0 + 16] : 0.0f;
#pragma unroll
    for (int r = 0; r < 4; ++r) {
        const int pout = pair_base + (lane >> 4) * 4 + r;
        out[(size_t)pout * 24 + o0] = acc0a[r] + acc0b[r] + bias0;
        if (o0 + 16 < 24)
            out[(size_t)pout * 24 + o0 + 16] = acc1a[r] + acc1b[r] + bias1;
    }
}

extern "C" void kernel_launch(void* const* d_in, const int* in_sizes, int n_in,
                              void* d_out, int out_size, void* d_ws, size_t ws_size,
                              hipStream_t stream) {
    const float* x      = (const float*)d_in[0];
    const int*   pos    = (const int*)d_in[1];
    const float* conv_w = (const float*)d_in[2];
    const float* conv_b = (const float*)d_in[3];
    const float* pred_w = (const float*)d_in[4];
    const float* pred_b = (const float*)d_in[5];
    float* out = (float*)d_out;

    char* ws = (char*)d_ws;
    unsigned short* h   = (unsigned short*)ws;                        // 67,108,864 B
    unsigned short* wb  = (unsigned short*)(ws + 67108864);           // 77,824 B
    unsigned short* pwb = (unsigned short*)(ws + 67108864 + 77824);   // 49,152 B

    prep_kernel<<<152, 256, 0, stream>>>(conv_w, pred_w, wb, pwb);
    conv_mfma<<<2048, 512, 0, stream>>>(x, wb, conv_b, h);
    gather_gemm<<<500, 256, 0, stream>>>(h, pos, pwb, pred_b, out);
}